// Round 2
// baseline (1132.988 us; speedup 1.0000x reference)
//
#include <hip/hip_runtime.h>
#include <math.h>

#define DEV_INLINE __device__ __forceinline__

DEV_INLINE float sigmoidf_(float x) { return 1.0f / (1.0f + expf(-x)); }

DEV_INLINE float wave_reduce(float v) {
#pragma unroll
    for (int off = 32; off; off >>= 1) v += __shfl_down(v, off, 64);
    return v;
}

// generic wave dot over nv float4 elements, 4 accumulators / 8 loads in flight
DEV_INLINE float wave_dotN(const float* __restrict__ row, const float* __restrict__ x,
                           int nv, int lane) {
    const float4* r4 = (const float4*)row;
    const float4* x4 = (const float4*)x;
    float a0 = 0.f, a1 = 0.f, a2 = 0.f, a3 = 0.f;
    int i = lane;
    for (; i + 192 < nv; i += 256) {
        float4 p0 = r4[i],       q0 = x4[i];
        float4 p1 = r4[i + 64],  q1 = x4[i + 64];
        float4 p2 = r4[i + 128], q2 = x4[i + 128];
        float4 p3 = r4[i + 192], q3 = x4[i + 192];
        a0 = fmaf(p0.x, q0.x, fmaf(p0.y, q0.y, fmaf(p0.z, q0.z, fmaf(p0.w, q0.w, a0))));
        a1 = fmaf(p1.x, q1.x, fmaf(p1.y, q1.y, fmaf(p1.z, q1.z, fmaf(p1.w, q1.w, a1))));
        a2 = fmaf(p2.x, q2.x, fmaf(p2.y, q2.y, fmaf(p2.z, q2.z, fmaf(p2.w, q2.w, a2))));
        a3 = fmaf(p3.x, q3.x, fmaf(p3.y, q3.y, fmaf(p3.z, q3.z, fmaf(p3.w, q3.w, a3))));
    }
    for (; i < nv; i += 64) {
        float4 p = r4[i], q = x4[i];
        a0 = fmaf(p.x, q.x, fmaf(p.y, q.y, fmaf(p.z, q.z, fmaf(p.w, q.w, a0))));
    }
    return wave_reduce(a0 + a1 + a2 + a3);
}

// column-reduction GEMV: out[0..1024) += sum_{r in [r0,r1)} A[r,:] * x[r]
// A row-major (rows x 1024); block=256, thread owns 4 consecutive cols.
DEV_INLINE void colgemv_block(const float* __restrict__ A, const float* __restrict__ x,
                              float* __restrict__ out, int r0, int r1) {
    int c4 = threadIdx.x;
    const float4* A4 = (const float4*)A;
    float4 s0 = make_float4(0.f, 0.f, 0.f, 0.f);
    float4 s1 = make_float4(0.f, 0.f, 0.f, 0.f);
    int r = r0;
    for (; r + 8 <= r1; r += 8) {
        float4 av[8];
        float xs[8];
#pragma unroll
        for (int k = 0; k < 8; ++k) av[k] = A4[(size_t)(r + k) * 256 + c4];
#pragma unroll
        for (int k = 0; k < 8; ++k) xs[k] = x[r + k];
#pragma unroll
        for (int k = 0; k < 8; ++k) {
            float4 a = av[k];
            float xv = xs[k];
            if (k & 1) {
                s1.x = fmaf(xv, a.x, s1.x); s1.y = fmaf(xv, a.y, s1.y);
                s1.z = fmaf(xv, a.z, s1.z); s1.w = fmaf(xv, a.w, s1.w);
            } else {
                s0.x = fmaf(xv, a.x, s0.x); s0.y = fmaf(xv, a.y, s0.y);
                s0.z = fmaf(xv, a.z, s0.z); s0.w = fmaf(xv, a.w, s0.w);
            }
        }
    }
    for (; r < r1; ++r) {
        float xv = x[r];
        float4 a = A4[(size_t)r * 256 + c4];
        s0.x = fmaf(xv, a.x, s0.x); s0.y = fmaf(xv, a.y, s0.y);
        s0.z = fmaf(xv, a.z, s0.z); s0.w = fmaf(xv, a.w, s0.w);
    }
    int c = c4 * 4;
    atomicAdd(out + c + 0, s0.x + s1.x);
    atomicAdd(out + c + 1, s0.y + s1.y);
    atomicAdd(out + c + 2, s0.z + s1.z);
    atomicAdd(out + c + 3, s0.w + s1.w);
}

// ---- device-scope flag sync (per-XCD L2 non-coherent -> fences + atomics) ----
// release: every thread fences its own writes, barrier, then tid0 bumps the flag
DEV_INLINE void signal_flag(int* f) {
    __threadfence();
    __syncthreads();
    if (threadIdx.x == 0) atomicAdd(f, 1);
}
// acquire: tid0 spins on coherent atomic read, barrier, then all threads fence
DEV_INLINE void wait_flag(int* f, int target) {
    if (threadIdx.x == 0) {
        while (atomicAdd(f, 0) < target) __builtin_amdgcn_s_sleep(127);
    }
    __syncthreads();
    __threadfence();
}

// Block roles (ascending blockIdx == dependency order; grid fully co-resident:
// 1835 blocks x 4 waves = 7340 waves <= 8192; launch_bounds(256,8) keeps VGPR<=64)
//  [0,50)      scores em[i,:]                         -> fSC (50)
//  [50,58)     softmax+alpha+cvec (wait fSC)          -> fAL (8)
//  [58,186)    W^T y   -> acc_st                      -> fMID
//  [186,314)   Wz^T y  -> acc_z                       -> fMID
//  [314,442)   Wr^T y  -> acc_r                       -> fR
//  [442,450)   Uz^T s  -> acc_z                       -> fMID
//  [450,458)   Ur^T s  -> acc_r                       -> fR
//  [458,474)   C^T c   (wait fAL)                     -> fMID
//  [474,490)   Cz^T c  (wait fAL)                     -> fMID
//  [490,506)   Cr^T c  (wait fAL)                     -> fR
//  [506,522)   U^T (sig(acc_r)*s) (wait fR=152)       -> fMID
//  [522,778)   Vo@y then (wait fAL) Co@c -> acc_t     -> fMID
//  [778,1034)  (wait fMID=568) snew, Uo@snew, tvec    -> fU
//  [1034,1834) (wait fU=256) Wo@tvec -> logits        -> fWO
//  [1834]      (wait fWO=800) log_softmax
__global__ __launch_bounds__(256, 8) void k_fused(
    const float* __restrict__ y, const float* __restrict__ s, const float* __restrict__ h,
    const float* __restrict__ W, const float* __restrict__ Wz, const float* __restrict__ Wr,
    const float* __restrict__ Wo, const float* __restrict__ U, const float* __restrict__ Uz,
    const float* __restrict__ Ur, const float* __restrict__ Uo, const float* __restrict__ C,
    const float* __restrict__ Cz, const float* __restrict__ Cr, const float* __restrict__ Co,
    const float* __restrict__ Vo, const float* __restrict__ Va, const float* __restrict__ Wa,
    const float* __restrict__ Ua, float* __restrict__ out, float* __restrict__ ws)
{
    float* acc_r  = ws;            // 1024 (zeroed)
    float* acc_z  = ws + 1024;     // 1024 (zeroed)
    float* acc_st = ws + 2048;     // 1024 (zeroed)
    float* acc_t  = ws + 3072;     // 4096 (zeroed; atomicAdd target)
    int*   flags  = (int*)(ws + 7168);   // 128 ints, 64B-line spaced (zeroed)
    float* em     = ws + 7296;     // 2560
    float* cvec   = ws + 9856;     // 2048
    float* tvec   = ws + 11904;    // 2048
    int* fSC  = flags;
    int* fAL  = flags + 16;
    int* fR   = flags + 32;
    int* fMID = flags + 48;
    int* fU   = flags + 64;
    int* fWO  = flags + 80;

    __shared__ float sm[1024];
    __shared__ float sred[8];
    __shared__ float sbval;

    const int bid  = blockIdx.x;
    const int tid  = threadIdx.x;
    const int w    = tid >> 6;
    const int lane = tid & 63;

    if (bid < 50) {                              // ---- scores ----
        int i = bid;
        for (int j = w; j < 50; j += 4) {
            float d1 = wave_dotN(Wa + j * 1024, s, 256, lane);
            float d2 = wave_dotN(Ua + j * 2048, h + i * 2048, 512, lane);
            if (lane == 0) em[i * 50 + j] = tanhf(d1 + d2);
        }
        signal_flag(fSC);
        return;
    }
    if (bid < 58) {                              // ---- softmax + alpha + cvec ----
        wait_flag(fSC, 50);
        if (tid < 64) {
            float sc = -1e30f;
            if (tid < 50) {
                float t = 0.f;
                for (int j = 0; j < 50; ++j) t = fmaf(Va[j], em[tid * 50 + j], t);
                sc = t;
            }
            float m = sc;
#pragma unroll
            for (int off = 32; off; off >>= 1) m = fmaxf(m, __shfl_xor(m, off, 64));
            float e = (tid < 50) ? expf(sc - m) : 0.f;
            float ssum = e;
#pragma unroll
            for (int off = 32; off; off >>= 1) ssum += __shfl_xor(ssum, off, 64);
            if (tid < 50) sm[tid] = e / ssum;
        }
        __syncthreads();
        int g = (bid - 50) * 256 + tid;
        float csum = 0.f;
        float* alpha_out = out + 17024;
        for (int i2 = 0; i2 < 50; ++i2) {
            float a = h[i2 * 2048 + g] * sm[i2];
            alpha_out[i2 * 2048 + g] = a;
            csum += a;
        }
        cvec[g] = csum;
        signal_flag(fAL);
        return;
    }
    if (bid < 186) { int b = bid - 58;  colgemv_block(W,  y, acc_st, b * 125, b * 125 + 125); signal_flag(fMID); return; }
    if (bid < 314) { int b = bid - 186; colgemv_block(Wz, y, acc_z,  b * 125, b * 125 + 125); signal_flag(fMID); return; }
    if (bid < 442) { int b = bid - 314; colgemv_block(Wr, y, acc_r,  b * 125, b * 125 + 125); signal_flag(fR);   return; }
    if (bid < 450) { int b = bid - 442; colgemv_block(Uz, s, acc_z,  b * 128, b * 128 + 128); signal_flag(fMID); return; }
    if (bid < 458) { int b = bid - 450; colgemv_block(Ur, s, acc_r,  b * 128, b * 128 + 128); signal_flag(fR);   return; }
    if (bid < 474) { int b = bid - 458; wait_flag(fAL, 8); colgemv_block(C,  cvec, acc_st, b * 128, b * 128 + 128); signal_flag(fMID); return; }
    if (bid < 490) { int b = bid - 474; wait_flag(fAL, 8); colgemv_block(Cz, cvec, acc_z,  b * 128, b * 128 + 128); signal_flag(fMID); return; }
    if (bid < 506) { int b = bid - 490; wait_flag(fAL, 8); colgemv_block(Cr, cvec, acc_r,  b * 128, b * 128 + 128); signal_flag(fR);   return; }
    if (bid < 522) {                             // ---- U^T (sigmoid(acc_r)*s) ----
        int b = bid - 506;
        wait_flag(fR, 152);
#pragma unroll
        for (int k = 0; k < 4; ++k) {
            int n = tid + 256 * k;
            sm[n] = sigmoidf_(acc_r[n]) * s[n];
        }
        __syncthreads();
        colgemv_block(U, sm, acc_st, b * 64, b * 64 + 64);
        signal_flag(fMID);
        return;
    }
    if (bid < 778) {                             // ---- Vo@y (+ Co@c) -> acc_t ----
        int b = bid - 522;
        int row0 = b * 16 + w * 4;
        float v1[4];
#pragma unroll
        for (int k = 0; k < 4; ++k)
            v1[k] = wave_dotN(Vo + (size_t)(row0 + k) * 16000, y, 4000, lane);
        wait_flag(fAL, 8);
#pragma unroll
        for (int k = 0; k < 4; ++k) {
            float v2 = wave_dotN(Co + (size_t)(row0 + k) * 2048, cvec, 512, lane);
            if (lane == 0) atomicAdd(acc_t + row0 + k, v1[k] + v2);
        }
        signal_flag(fMID);
        return;
    }
    if (bid < 1034) {                            // ---- snew + Uo + tvec ----
        int b = bid - 778;
        wait_flag(fMID, 568);
#pragma unroll
        for (int k = 0; k < 4; ++k) {
            int n = tid + 256 * k;
            float z  = sigmoidf_(acc_z[n]);
            float st = sigmoidf_(acc_st[n]);
            float v = (1.f - z) * s[n] + z * st;
            sm[n] = v;
            if (b == 0) out[16000 + n] = v;
        }
        __syncthreads();
        float m0 = 0.f;
#pragma unroll
        for (int k = 0; k < 4; ++k) {
            int row = b * 16 + w * 4 + k;
            float d = wave_dotN(Uo + (size_t)row * 1024, sm, 256, lane);
            if (lane == 0) {
                float tf = sigmoidf_(acc_t[row] + d);
                if (k & 1) tvec[row >> 1] = fmaxf(m0, tf);
                else       m0 = tf;
            }
        }
        signal_flag(fU);
        return;
    }
    if (bid < 1834) {                            // ---- Wo @ tvec -> logits ----
        int b = bid - 1034;
        wait_flag(fU, 256);
        int gw = b * 4 + w;
#pragma unroll
        for (int k = 0; k < 5; ++k) {
            int row = gw * 5 + k;
            float v = wave_dotN(Wo + (size_t)row * 2048, tvec, 512, lane);
            if (lane == 0) out[row] = v;
        }
        signal_flag(fWO);
        return;
    }
    // ---- log_softmax over 16000 logits (single block) ----
    wait_flag(fWO, 800);
    {
        float4* o4 = (float4*)out;               // 4000 float4 = 16000 exactly
        float m = -1e30f;
        for (int i = tid; i < 4000; i += 256) {
            float4 v = o4[i];
            m = fmaxf(m, fmaxf(fmaxf(v.x, v.y), fmaxf(v.z, v.w)));
        }
#pragma unroll
        for (int off = 32; off; off >>= 1) m = fmaxf(m, __shfl_xor(m, off, 64));
        if (lane == 0) sred[w] = m;
        __syncthreads();
        if (tid == 0) sbval = fmaxf(fmaxf(sred[0], sred[1]), fmaxf(sred[2], sred[3]));
        __syncthreads();
        float M = sbval;
        float sum = 0.f;
        for (int i = tid; i < 4000; i += 256) {
            float4 v = o4[i];
            sum += expf(v.x - M) + expf(v.y - M) + expf(v.z - M) + expf(v.w - M);
        }
#pragma unroll
        for (int off = 32; off; off >>= 1) sum += __shfl_xor(sum, off, 64);
        if (lane == 0) sred[w] = sum;
        __syncthreads();
        if (tid == 0) sbval = M + logf(sred[0] + sred[1] + sred[2] + sred[3]);
        __syncthreads();
        float lse = sbval;
        for (int i = tid; i < 4000; i += 256) {
            float4 v = o4[i];
            v.x -= lse; v.y -= lse; v.z -= lse; v.w -= lse;
            o4[i] = v;
        }
    }
}

extern "C" void kernel_launch(void* const* d_in, const int* in_sizes, int n_in,
                              void* d_out, int out_size, void* d_ws, size_t ws_size,
                              hipStream_t stream) {
    const float* y  = (const float*)d_in[0];
    const float* s  = (const float*)d_in[1];
    const float* h  = (const float*)d_in[2];
    const float* W  = (const float*)d_in[3];
    const float* Wz = (const float*)d_in[4];
    const float* Wr = (const float*)d_in[5];
    const float* Wo = (const float*)d_in[6];
    const float* U  = (const float*)d_in[7];
    const float* Uz = (const float*)d_in[8];
    const float* Ur = (const float*)d_in[9];
    const float* Uo = (const float*)d_in[10];
    const float* C  = (const float*)d_in[11];
    const float* Cz = (const float*)d_in[12];
    const float* Cr = (const float*)d_in[13];
    const float* Co = (const float*)d_in[14];
    const float* Vo = (const float*)d_in[15];
    const float* Va = (const float*)d_in[16];
    const float* Wa = (const float*)d_in[17];
    const float* Ua = (const float*)d_in[18];

    float* out = (float*)d_out;   // [0,16000) log_sm | [16000,17024) s_new | [17024,119424) alpha
    float* ws  = (float*)d_ws;

    // zero accumulators + flags (acc_r/z/st 3072, acc_t 4096, flags 128 ints)
    hipMemsetAsync(ws, 0, 7296 * sizeof(float), stream);
    k_fused<<<1835, 256, 0, stream>>>(y, s, h, W, Wz, Wr, Wo, U, Uz, Ur, Uo,
                                      C, Cz, Cr, Co, Vo, Va, Wa, Ua, out, ws);
}